// Round 1
// baseline (229.565 us; speedup 1.0000x reference)
//
#include <hip/hip_runtime.h>
#include <float.h>
#include <math.h>

#define Bc 512
#define Sc 100
#define Hc 1024
#define Ac 128
#define Nc 8

// ---------------- K0a: positional-encoding table pe[S][H] ----------------
__global__ __launch_bounds__(256) void pe_kernel(float* __restrict__ pe){
  int s = blockIdx.x;
  int t = threadIdx.x;
  const float fac = (float)(-9.210340371976184 / 1024.0);  // -ln(10000)/H, rounded like jnp
  for(int i = t; i < Hc/2; i += 256){
    float div = expf((float)(2*i) * fac);
    float a = (float)s * div;
    pe[s*Hc + 2*i]     = sinf(a);
    pe[s*Hc + 2*i + 1] = cosf(a);
  }
}

// ---------------- K0b: pesum[h] = sum_s pe[s][h] ----------------
__global__ __launch_bounds__(256) void pesum_kernel(const float* __restrict__ pe, float* __restrict__ pesum){
  int h = blockIdx.x*256 + threadIdx.x;
  float acc = 0.f;
  for(int s = 0; s < Sc; ++s) acc += pe[s*Hc + h];
  pesum[h] = acc;
}

// ---------------- K1: xsum[b][h] = sum_s x[b,s,h] + pesum[h] ----------------
__global__ __launch_bounds__(256) void xsum_kernel(const float* __restrict__ x, const float* __restrict__ pesum,
                                                   float* __restrict__ xsum){
  int b = blockIdx.x;
  int t = threadIdx.x;                          // t -> h = 4t..4t+3
  const float4* xr = (const float4*)(x + (size_t)b*Sc*Hc);
  float4 acc = ((const float4*)pesum)[t];
  #pragma unroll 4
  for(int s = 0; s < Sc; ++s){
    float4 v = xr[s*(Hc/4) + t];
    acc.x += v.x; acc.y += v.y; acc.z += v.z; acc.w += v.w;
  }
  ((float4*)(xsum + (size_t)b*Hc))[t] = acc;
}

// ---------------- K2: Ksum[b][j] = sum_h xsum[b][h] * Wk[j][h]  (NT GEMM, 32x64 tile) ----------------
__global__ __launch_bounds__(256) void ksum_gemm(const float* __restrict__ xs, const float* __restrict__ Wk,
                                                 float* __restrict__ Ksum){
  __shared__ float As[32][33];   // [k][b]
  __shared__ float Bs[32][68];   // [k][j]  (stride 68 -> 272B rows, float4-aligned)
  int t = threadIdx.x;
  int j0 = blockIdx.x*64, b0 = blockIdx.y*32;
  int bi = (t>>4)*2;
  int j4 = (t&15)*4;
  float acc[2][4] = {{0,0,0,0},{0,0,0,0}};
  int ra = t>>3, ca = t&7;
  for(int k0 = 0; k0 < Hc; k0 += 32){
    float4 a4 = *(const float4*)(xs + (size_t)(b0+ra)*Hc + k0 + ca*4);
    As[ca*4+0][ra]=a4.x; As[ca*4+1][ra]=a4.y; As[ca*4+2][ra]=a4.z; As[ca*4+3][ra]=a4.w;
    #pragma unroll
    for(int ph = 0; ph < 2; ++ph){
      int q = t + ph*256;
      int r = q>>3, c = q&7;
      float4 b4 = *(const float4*)(Wk + (size_t)(j0+r)*Hc + k0 + c*4);
      Bs[c*4+0][r]=b4.x; Bs[c*4+1][r]=b4.y; Bs[c*4+2][r]=b4.z; Bs[c*4+3][r]=b4.w;
    }
    __syncthreads();
    #pragma unroll
    for(int kk = 0; kk < 32; ++kk){
      float a0 = As[kk][bi], a1 = As[kk][bi+1];
      float4 bq = *(const float4*)&Bs[kk][j4];
      acc[0][0]=fmaf(a0,bq.x,acc[0][0]); acc[0][1]=fmaf(a0,bq.y,acc[0][1]);
      acc[0][2]=fmaf(a0,bq.z,acc[0][2]); acc[0][3]=fmaf(a0,bq.w,acc[0][3]);
      acc[1][0]=fmaf(a1,bq.x,acc[1][0]); acc[1][1]=fmaf(a1,bq.y,acc[1][1]);
      acc[1][2]=fmaf(a1,bq.z,acc[1][2]); acc[1][3]=fmaf(a1,bq.w,acc[1][3]);
    }
    __syncthreads();
  }
  #pragma unroll
  for(int ii = 0; ii < 2; ++ii){
    float4 o = make_float4(acc[ii][0],acc[ii][1],acc[ii][2],acc[ii][3]);
    *(float4*)(Ksum + (size_t)(b0+bi+ii)*Hc + j0 + j4) = o;
  }
}

// ---------------- K3: v[b][n][h] = sum_a Ksum[b][n*A+a] * Wq[n*A+a][h] ----------------
__global__ __launch_bounds__(256) void v_gemm(const float* __restrict__ Ksum, const float* __restrict__ Wq,
                                              float* __restrict__ v){
  __shared__ float As[32][33];   // [a][b]
  __shared__ float Bs[32][68];   // [a][h]
  int t = threadIdx.x;
  int h0 = blockIdx.x*64, b0 = blockIdx.y*32, n = blockIdx.z;
  int bi = (t>>4)*2;
  int j4 = (t&15)*4;
  float acc[2][4] = {{0,0,0,0},{0,0,0,0}};
  int ra = t>>3, ca = t&7;
  for(int k0 = 0; k0 < Ac; k0 += 32){
    float4 a4 = *(const float4*)(Ksum + (size_t)(b0+ra)*Hc + n*Ac + k0 + ca*4);
    As[ca*4+0][ra]=a4.x; As[ca*4+1][ra]=a4.y; As[ca*4+2][ra]=a4.z; As[ca*4+3][ra]=a4.w;
    #pragma unroll
    for(int ph = 0; ph < 2; ++ph){
      int q = t + ph*256;
      int r = q>>4, c = q&15;   // r: a-row 0..31, c: h-chunk 0..15
      float4 b4 = *(const float4*)(Wq + (size_t)(n*Ac + k0 + r)*Hc + h0 + c*4);
      *(float4*)&Bs[r][c*4] = b4;
    }
    __syncthreads();
    #pragma unroll
    for(int kk = 0; kk < 32; ++kk){
      float a0 = As[kk][bi], a1 = As[kk][bi+1];
      float4 bq = *(const float4*)&Bs[kk][j4];
      acc[0][0]=fmaf(a0,bq.x,acc[0][0]); acc[0][1]=fmaf(a0,bq.y,acc[0][1]);
      acc[0][2]=fmaf(a0,bq.z,acc[0][2]); acc[0][3]=fmaf(a0,bq.w,acc[0][3]);
      acc[1][0]=fmaf(a1,bq.x,acc[1][0]); acc[1][1]=fmaf(a1,bq.y,acc[1][1]);
      acc[1][2]=fmaf(a1,bq.z,acc[1][2]); acc[1][3]=fmaf(a1,bq.w,acc[1][3]);
    }
    __syncthreads();
  }
  #pragma unroll
  for(int ii = 0; ii < 2; ++ii){
    float4 o = make_float4(acc[ii][0],acc[ii][1],acc[ii][2],acc[ii][3]);
    *(float4*)(v + ((size_t)(b0+bi+ii)*Nc + n)*Hc + h0 + j4) = o;
  }
}

// ---------------- K4: logits -> +gumbel -> argmax_s -> gather rows of x ----------------
// one block per b. 4 waves: (s_half, k_half). Lane owns one s; accumulates full dots
// over its k-half for all 8 heads; partials combined through LDS; fused gather.
__global__ __launch_bounds__(256) void attn_kernel(const float* __restrict__ x, const float* __restrict__ pe,
                                                   const float* __restrict__ v, const float* __restrict__ g,
                                                   float* __restrict__ out){
  __shared__ float4 partq[4*128];  // [k_half][n-quad][s]
  __shared__ int sidx[Nc];
  int b = blockIdx.x;
  int t = threadIdx.x;
  int w = t >> 6, lane = t & 63;
  int s_half = w >> 1, k_half = w & 1;
  int s = s_half*64 + lane;              // 0..127 (>=100 are dummies, clamped loads)
  int s_ld = (s < Sc) ? s : (Sc-1);

  const float4* xrow  = (const float4*)(x  + ((size_t)b*Sc + s_ld)*Hc);
  const float4* perow = (const float4*)(pe + (size_t)s_ld*Hc);
  const float4* vb    = (const float4*)(v  + (size_t)b*Nc*Hc);

  float acc[Nc];
  #pragma unroll
  for(int n = 0; n < Nc; ++n) acc[n] = 0.f;

  int kc0 = k_half*128;
  for(int kc = kc0; kc < kc0 + 128; ++kc){
    float4 xv = xrow[kc];
    float4 pv = perow[kc];
    float4 xe = make_float4(xv.x+pv.x, xv.y+pv.y, xv.z+pv.z, xv.w+pv.w);
    #pragma unroll
    for(int n = 0; n < Nc; ++n){
      float4 vv = vb[n*(Hc/4) + kc];   // wave-uniform address
      acc[n] = fmaf(xe.x, vv.x, acc[n]);
      acc[n] = fmaf(xe.y, vv.y, acc[n]);
      acc[n] = fmaf(xe.z, vv.z, acc[n]);
      acc[n] = fmaf(xe.w, vv.w, acc[n]);
    }
  }
  partq[(k_half*2 + 0)*128 + s] = make_float4(acc[0],acc[1],acc[2],acc[3]);
  partq[(k_half*2 + 1)*128 + s] = make_float4(acc[4],acc[5],acc[6],acc[7]);
  __syncthreads();

  // phase 2: y = dot/3200 + gumbel; argmax over s per (b,n)
  int n = t >> 5, j = t & 31;
  const float* pf = (const float*)partq;
  float best = -FLT_MAX; int bidx = 0;
  #pragma unroll
  for(int i = 0; i < 4; ++i){
    int s2 = j + 32*i;
    if(s2 < Sc){
      float dot = pf[((n>>2)*128 + s2)*4 + (n&3)] + pf[((2 + (n>>2))*128 + s2)*4 + (n&3)];
      float y = dot/3200.0f + g[(size_t)(b*Nc + n)*Sc + s2];
      if(y > best){ best = y; bidx = s2; }   // strict > keeps first index (jnp.argmax tie rule)
    }
  }
  #pragma unroll
  for(int m = 16; m >= 1; m >>= 1){
    float ob = __shfl_xor(best, m, 32);
    int   oi = __shfl_xor(bidx, m, 32);
    if(ob > best || (ob == best && oi < bidx)){ best = ob; bidx = oi; }
  }
  if(j == 0) sidx[n] = bidx;
  __syncthreads();

  // phase 3: out[b,n,:] = x[b, s*, :]
  const float4* xb = (const float4*)(x + (size_t)b*Sc*Hc);
  float4* ob4 = (float4*)(out + (size_t)b*Nc*Hc);
  #pragma unroll
  for(int nn = 0; nn < Nc; ++nn){
    int ss = sidx[nn];
    ob4[nn*(Hc/4) + t] = xb[ss*(Hc/4) + t];
  }
}

extern "C" void kernel_launch(void* const* d_in, const int* in_sizes, int n_in,
                              void* d_out, int out_size, void* d_ws, size_t ws_size,
                              hipStream_t stream) {
  const float* x  = (const float*)d_in[0];   // [512,100,1024]
  const float* Wq = (const float*)d_in[1];   // [1024,1024]
  const float* Wk = (const float*)d_in[2];   // [1024,1024]
  const float* g  = (const float*)d_in[3];   // [4096,100]
  float* out = (float*)d_out;                // [512,8,1024]

  char* ws = (char*)d_ws;
  float* pe    = (float*)(ws);               //   409,600 B
  float* pesum = (float*)(ws +   409600);    //     4,096 B
  float* xsum  = (float*)(ws +   413696);    // 2,097,152 B
  float* Ksum  = (float*)(ws +  2510848);    // 2,097,152 B
  float* v     = (float*)(ws +  4608000);    // 16,777,216 B   (total ~21.4 MB)

  pe_kernel   <<<100, 256, 0, stream>>>(pe);
  pesum_kernel<<<4,   256, 0, stream>>>(pe, pesum);
  xsum_kernel <<<512, 256, 0, stream>>>(x, pesum, xsum);
  ksum_gemm   <<<dim3(16,16),   256, 0, stream>>>(xsum, Wk, Ksum);
  v_gemm      <<<dim3(16,16,8), 256, 0, stream>>>(Ksum, Wq, v);
  attn_kernel <<<512, 256, 0, stream>>>(x, pe, v, g, out);
}

// Round 2
// 182.374 us; speedup vs baseline: 1.2588x; 1.2588x over previous
//
#include <hip/hip_runtime.h>
#include <float.h>
#include <math.h>

#define Bc 512
#define Sc 100
#define Hc 1024
#define Ac 128
#define Nc 8

// ---------------- K0a: positional-encoding table pe[S][H] ----------------
__global__ __launch_bounds__(256) void pe_kernel(float* __restrict__ pe){
  int s = blockIdx.x;
  int t = threadIdx.x;
  const float fac = (float)(-9.210340371976184 / 1024.0);  // -ln(10000)/H
  for(int i = t; i < Hc/2; i += 256){
    float div = expf((float)(2*i) * fac);
    float a = (float)s * div;
    pe[s*Hc + 2*i]     = sinf(a);
    pe[s*Hc + 2*i + 1] = cosf(a);
  }
}

// ---------------- K0b: pesum[h] = sum_s pe[s][h] ----------------
__global__ __launch_bounds__(256) void pesum_kernel(const float* __restrict__ pe, float* __restrict__ pesum){
  int h = blockIdx.x*256 + threadIdx.x;
  float acc = 0.f;
  for(int s = 0; s < Sc; ++s) acc += pe[s*Hc + h];
  pesum[h] = acc;
}

// ---------------- K1: xsp[b][q][h] = sum_{s in quarter q} x[b,s,h]  (+pesum at q==0) ----------------
// grid (512, 4) x 256 threads -> 8 blocks/CU, full occupancy.
__global__ __launch_bounds__(256) void xsum_kernel(const float* __restrict__ x, const float* __restrict__ pesum,
                                                   float* __restrict__ xsp){
  int b = blockIdx.x;
  int q = blockIdx.y;
  int t = threadIdx.x;                          // t -> h = 4t..4t+3
  const float4* xr = (const float4*)(x + (size_t)b*Sc*Hc);
  float4 acc;
  if(q == 0) acc = ((const float4*)pesum)[t];
  else       acc = make_float4(0.f,0.f,0.f,0.f);
  int s0 = q*25;
  #pragma unroll 5
  for(int s = s0; s < s0+25; ++s){
    float4 v = xr[s*(Hc/4) + t];
    acc.x += v.x; acc.y += v.y; acc.z += v.z; acc.w += v.w;
  }
  ((float4*)(xsp + ((size_t)b*4 + q)*Hc))[t] = acc;
}

// ---------------- K2: Ksum[b][j] = sum_h (sum_q xsp[b][q][h]) * Wk[j][h] ----------------
__global__ __launch_bounds__(256) void ksum_gemm(const float* __restrict__ xs, const float* __restrict__ Wk,
                                                 float* __restrict__ Ksum){
  __shared__ float As[32][33];   // [k][b]
  __shared__ float Bs[32][68];   // [k][j]
  int t = threadIdx.x;
  int j0 = blockIdx.x*64, b0 = blockIdx.y*32;
  int bi = (t>>4)*2;
  int j4 = (t&15)*4;
  float acc[2][4] = {{0,0,0,0},{0,0,0,0}};
  int ra = t>>3, ca = t&7;
  for(int k0 = 0; k0 < Hc; k0 += 32){
    const float* xa = xs + (size_t)(b0+ra)*(4*Hc) + k0 + ca*4;
    float4 a4 = *(const float4*)(xa);
    float4 p1 = *(const float4*)(xa + Hc);
    float4 p2 = *(const float4*)(xa + 2*Hc);
    float4 p3 = *(const float4*)(xa + 3*Hc);
    a4.x += p1.x + p2.x + p3.x;
    a4.y += p1.y + p2.y + p3.y;
    a4.z += p1.z + p2.z + p3.z;
    a4.w += p1.w + p2.w + p3.w;
    As[ca*4+0][ra]=a4.x; As[ca*4+1][ra]=a4.y; As[ca*4+2][ra]=a4.z; As[ca*4+3][ra]=a4.w;
    #pragma unroll
    for(int ph = 0; ph < 2; ++ph){
      int q = t + ph*256;
      int r = q>>3, c = q&7;
      float4 b4 = *(const float4*)(Wk + (size_t)(j0+r)*Hc + k0 + c*4);
      Bs[c*4+0][r]=b4.x; Bs[c*4+1][r]=b4.y; Bs[c*4+2][r]=b4.z; Bs[c*4+3][r]=b4.w;
    }
    __syncthreads();
    #pragma unroll
    for(int kk = 0; kk < 32; ++kk){
      float a0 = As[kk][bi], a1 = As[kk][bi+1];
      float4 bq = *(const float4*)&Bs[kk][j4];
      acc[0][0]=fmaf(a0,bq.x,acc[0][0]); acc[0][1]=fmaf(a0,bq.y,acc[0][1]);
      acc[0][2]=fmaf(a0,bq.z,acc[0][2]); acc[0][3]=fmaf(a0,bq.w,acc[0][3]);
      acc[1][0]=fmaf(a1,bq.x,acc[1][0]); acc[1][1]=fmaf(a1,bq.y,acc[1][1]);
      acc[1][2]=fmaf(a1,bq.z,acc[1][2]); acc[1][3]=fmaf(a1,bq.w,acc[1][3]);
    }
    __syncthreads();
  }
  #pragma unroll
  for(int ii = 0; ii < 2; ++ii){
    float4 o = make_float4(acc[ii][0],acc[ii][1],acc[ii][2],acc[ii][3]);
    *(float4*)(Ksum + (size_t)(b0+bi+ii)*Hc + j0 + j4) = o;
  }
}

// ---------------- K3: v[b][n][h] = sum_a Ksum[b][n*A+a] * Wq[n*A+a][h] ----------------
__global__ __launch_bounds__(256) void v_gemm(const float* __restrict__ Ksum, const float* __restrict__ Wq,
                                              float* __restrict__ v){
  __shared__ float As[32][33];   // [a][b]
  __shared__ float Bs[32][68];   // [a][h]
  int t = threadIdx.x;
  int h0 = blockIdx.x*64, b0 = blockIdx.y*32, n = blockIdx.z;
  int bi = (t>>4)*2;
  int j4 = (t&15)*4;
  float acc[2][4] = {{0,0,0,0},{0,0,0,0}};
  int ra = t>>3, ca = t&7;
  for(int k0 = 0; k0 < Ac; k0 += 32){
    float4 a4 = *(const float4*)(Ksum + (size_t)(b0+ra)*Hc + n*Ac + k0 + ca*4);
    As[ca*4+0][ra]=a4.x; As[ca*4+1][ra]=a4.y; As[ca*4+2][ra]=a4.z; As[ca*4+3][ra]=a4.w;
    #pragma unroll
    for(int ph = 0; ph < 2; ++ph){
      int q = t + ph*256;
      int r = q>>4, c = q&15;
      float4 b4 = *(const float4*)(Wq + (size_t)(n*Ac + k0 + r)*Hc + h0 + c*4);
      *(float4*)&Bs[r][c*4] = b4;
    }
    __syncthreads();
    #pragma unroll
    for(int kk = 0; kk < 32; ++kk){
      float a0 = As[kk][bi], a1 = As[kk][bi+1];
      float4 bq = *(const float4*)&Bs[kk][j4];
      acc[0][0]=fmaf(a0,bq.x,acc[0][0]); acc[0][1]=fmaf(a0,bq.y,acc[0][1]);
      acc[0][2]=fmaf(a0,bq.z,acc[0][2]); acc[0][3]=fmaf(a0,bq.w,acc[0][3]);
      acc[1][0]=fmaf(a1,bq.x,acc[1][0]); acc[1][1]=fmaf(a1,bq.y,acc[1][1]);
      acc[1][2]=fmaf(a1,bq.z,acc[1][2]); acc[1][3]=fmaf(a1,bq.w,acc[1][3]);
    }
    __syncthreads();
  }
  #pragma unroll
  for(int ii = 0; ii < 2; ++ii){
    float4 o = make_float4(acc[ii][0],acc[ii][1],acc[ii][2],acc[ii][3]);
    *(float4*)(v + ((size_t)(b0+bi+ii)*Nc + n)*Hc + h0 + j4) = o;
  }
}

// ---------------- K4: logits -> +gumbel -> argmax_s -> gather rows of x ----------------
// One block (512 thr = 8 waves) per b. v[b] staged in LDS (32KB) so the hot loop
// issues only 2 VMEM loads/iter. Waves = (s_half, k_quarter); LDS combine; fused gather.
__global__ __launch_bounds__(512) void attn_kernel(const float* __restrict__ x, const float* __restrict__ pe,
                                                   const float* __restrict__ v, const float* __restrict__ g,
                                                   float* __restrict__ out){
  __shared__ float vsh[Nc*Hc];        // 32 KB
  __shared__ float part[4][Nc][128];  // 16 KB
  __shared__ int sidx[Nc];
  int b = blockIdx.x;
  int t = threadIdx.x;

  // stage v[b] -> LDS
  const float4* vb4 = (const float4*)(v + (size_t)b*Nc*Hc);
  float4* vsh4 = (float4*)vsh;
  #pragma unroll
  for(int i = 0; i < 4; ++i) vsh4[t + i*512] = vb4[t + i*512];
  __syncthreads();

  int w = t >> 6, lane = t & 63;
  int s_half = w >> 2, kq = w & 3;
  int s = s_half*64 + lane;              // 0..127 (>=100 dummies, clamped loads)
  int s_ld = (s < Sc) ? s : (Sc-1);

  const float4* xrow  = (const float4*)(x  + ((size_t)b*Sc + s_ld)*Hc);
  const float4* perow = (const float4*)(pe + (size_t)s_ld*Hc);

  float acc[Nc];
  #pragma unroll
  for(int n = 0; n < Nc; ++n) acc[n] = 0.f;

  int kc0 = kq*64;                       // float4 index; each wave owns 64 of 256
  #pragma unroll 4
  for(int kc = kc0; kc < kc0 + 64; ++kc){
    float4 xv = xrow[kc];
    float4 pv = perow[kc];
    float4 xe = make_float4(xv.x+pv.x, xv.y+pv.y, xv.z+pv.z, xv.w+pv.w);
    #pragma unroll
    for(int n = 0; n < Nc; ++n){
      float4 vv = *(const float4*)(vsh + n*Hc + kc*4);   // wave-uniform LDS broadcast
      acc[n] = fmaf(xe.x, vv.x, acc[n]);
      acc[n] = fmaf(xe.y, vv.y, acc[n]);
      acc[n] = fmaf(xe.z, vv.z, acc[n]);
      acc[n] = fmaf(xe.w, vv.w, acc[n]);
    }
  }
  #pragma unroll
  for(int n = 0; n < Nc; ++n) part[kq][n][s] = acc[n];   // stride-1 across lanes
  __syncthreads();

  // phase 2: y = dot/3200 + gumbel; argmax over s. One wave per head n.
  int n = w, j = lane;
  float best = -FLT_MAX; int bidx = 0;
  #pragma unroll
  for(int i = 0; i < 2; ++i){
    int s2 = j + 64*i;
    if(s2 < Sc){
      float dot = part[0][n][s2] + part[1][n][s2] + part[2][n][s2] + part[3][n][s2];
      float y = dot/3200.0f + g[(size_t)(b*Nc + n)*Sc + s2];
      if(y > best){ best = y; bidx = s2; }   // strict > keeps first index (jnp tie rule)
    }
  }
  #pragma unroll
  for(int m = 32; m >= 1; m >>= 1){
    float ob = __shfl_xor(best, m, 64);
    int   oi = __shfl_xor(bidx, m, 64);
    if(ob > best || (ob == best && oi < bidx)){ best = ob; bidx = oi; }
  }
  if(j == 0) sidx[n] = bidx;
  __syncthreads();

  // phase 3: out[b,n,:] = x[b, s*, :]  (2048 float4 over 512 threads)
  const float4* xb = (const float4*)(x + (size_t)b*Sc*Hc);
  float4* ob4 = (float4*)(out + (size_t)b*Nc*Hc);
  #pragma unroll
  for(int i = 0; i < 4; ++i){
    int idx = i*512 + t;
    int nn = idx >> 8, c = idx & 255;
    ob4[idx] = xb[sidx[nn]*256 + c];
  }
}

extern "C" void kernel_launch(void* const* d_in, const int* in_sizes, int n_in,
                              void* d_out, int out_size, void* d_ws, size_t ws_size,
                              hipStream_t stream) {
  const float* x  = (const float*)d_in[0];   // [512,100,1024]
  const float* Wq = (const float*)d_in[1];   // [1024,1024]
  const float* Wk = (const float*)d_in[2];   // [1024,1024]
  const float* g  = (const float*)d_in[3];   // [4096,100]
  float* out = (float*)d_out;                // [512,8,1024]

  char* ws = (char*)d_ws;
  float* pe    = (float*)(ws);                //    409,600 B
  float* pesum = (float*)(ws +    409600);    //      4,096 B
  float* xsp   = (float*)(ws +    413696);    //  8,388,608 B  [512][4][1024]
  float* Ksum  = (float*)(ws +   8802304);    //  2,097,152 B
  float* v     = (float*)(ws +  10899456);    // 16,777,216 B  (total ~27.7 MB)

  pe_kernel   <<<100, 256, 0, stream>>>(pe);
  pesum_kernel<<<4,   256, 0, stream>>>(pe, pesum);
  xsum_kernel <<<dim3(512,4),   256, 0, stream>>>(x, pesum, xsp);
  ksum_gemm   <<<dim3(16,16),   256, 0, stream>>>(xsp, Wk, Ksum);
  v_gemm      <<<dim3(16,16,8), 256, 0, stream>>>(Ksum, Wq, v);
  attn_kernel <<<512, 512, 0, stream>>>(x, pe, v, g, out);
}